// Round 5
// baseline (234.976 us; speedup 1.0000x reference)
//
#include <hip/hip_runtime.h>

// Triplet loss: mean(relu(|(a-p)W|^2 - |(a-n)W|^2 + 0.2)); bias cancels.
//
// R7 = R6 + sustained (non-duty-cycled) per-wave memory pipeline.
// Post-mortem R6: traffic 521->373 MB bought only 2% (93.5->91.3us);
// delivered vmem BW tracks waves/CU (R2 16w:5.2, R4 8w:5.6, R6 4w:4.1
// TB/s) with every pipe <20% busy -> CONCURRENCY-limited, not
// throughput-limited. R6's wave was duty-cycled: vmcnt(12) also waited
// on the just-issued W loads (older than stage(c+1)), and the two
// 6-read lds asm blocks serialized two LDS round-trips.
// R7 fixes: (1) W fragments double-buffered in regs, prefetched a chunk
// ahead -> in-loop wait vmcnt(28) (= 8 W(c) + 12 stage(c+1) + 8 W(c+1)
// younger than stage(c)) never waits on fresh loads; the compiler's own
// counted wait for wf use lands at vmcnt(20), draining nothing.
// (2) single 12x ds_read_b128 asm + one lgkmcnt(0). Wave now blocks at
// the vmcnt with 20KB genuinely outstanding -> 80KB/CU sustained.
// VGPR ~270 (acc 128 + 2x32 wf + 48 temps) is free at 1 wave/SIMD.
// Everything else = R6: 96KB LDS, 4 waves, MT=2 m-tiles (W amortized),
// grid 256 = 1 block/CU single round, no barriers in main loop.
//
// Layout (gfx950, mfma_f32_16x16x32_bf16):
//   A: lane holds A[m=lane&15][k=(lane>>4)*8+j]  (8 bf16)
//   B: lane holds B[k=(lane>>4)*8+j][n=lane&15]
//   C/D: lane holds D[row=(lane>>4)*4+reg][col=lane&15]

#define KDIM  2304   // 48*48
#define EMBD  128
#define BATCH 8192
#define NT    8      // 128 / 16 n-tiles
#define NW    4      // waves per block
#define MT    2      // 16-row m-tiles per wave (M=32/block)
#define CPW   18     // K-chunks (of 32) per wave: 72/4  (even: 2-phase unroll)
#define ALPHA 0.2f

typedef __attribute__((ext_vector_type(8))) short short8;
typedef __attribute__((ext_vector_type(4))) float f32x4;
typedef __attribute__((ext_vector_type(4))) unsigned int u32x4;

#define AS1 __attribute__((address_space(1)))
#define AS3 __attribute__((address_space(3)))

__device__ __forceinline__ unsigned short f2bf(float f) {
    unsigned u = __builtin_bit_cast(unsigned, f);
    u += 0x7FFFu + ((u >> 16) & 1u);       // round-to-nearest-even
    return (unsigned short)(u >> 16);
}

// Coalesced-read pack: Wp[((c*8+t)*64+l)*8+j] = bf16(W[k][n]),
// k = c*32 + (l>>4)*8 + j, n = t*16 + (l&15).   (unchanged)
__global__ void pack_w_kernel(const float* __restrict__ W,
                              unsigned short* __restrict__ Wp) {
    int tid = blockIdx.x * blockDim.x + threadIdx.x;   // 0 .. 2304*128-1
    int n = tid & 127;
    int k = tid >> 7;
    int c = k >> 5;
    int q = (k >> 3) & 3;
    int j = k & 7;
    int t = n >> 4;
    int l = q * 16 + (n & 15);
    Wp[(size_t)(((c * 8 + t) * 64) + l) * 8 + j] = f2bf(W[tid]);
}

__device__ __forceinline__ unsigned cvtpk(float lo, float hi) {
    unsigned r;
    asm("v_cvt_pk_bf16_f32 %0, %1, %2" : "=v"(r) : "v"(lo), "v"(hi));
    return r;
}

// 16B/lane global->LDS DMA: LDS dest = uniform base + lane*16,
// global src is per-lane (pre-swizzled into fragment order).
__device__ __forceinline__ void gll16(const float* g, char* l) {
    __builtin_amdgcn_global_load_lds((AS1 void*)(void*)g, (AS3 void*)l, 16, 0, 0);
}

__global__ __launch_bounds__(256, 1) void triplet_kernel(
    const float* __restrict__ A, const float* __restrict__ P,
    const float* __restrict__ Ng, const unsigned short* __restrict__ Wp,
    float* __restrict__ out)
{
    // 4 waves x (2 bufs x 12KB) staging = 96KB; reduce tree aliased.
    __shared__ __align__(16) char smem[NW * 24576];

    const int lane = threadIdx.x & 63;
    const int wave = threadIdx.x >> 6;
    const int c0   = wave * CPW;             // this wave's first K-chunk

    // Per-lane global bases in fragment order, one per m-tile:
    // row = blk*32 + mt*16 + (lane&15), col = (lane>>4)*8 floats.
    const size_t goff0 = (size_t)(blockIdx.x * 32 + (lane & 15)) * KDIM
                       + (size_t)(lane >> 4) * 8 + (size_t)c0 * 32;
    const size_t goff1 = goff0 + (size_t)16 * KDIM;
    const float* gA0 = A  + goff0;  const float* gA1 = A  + goff1;
    const float* gP0 = P  + goff0;  const float* gP1 = P  + goff1;
    const float* gN0 = Ng + goff0;  const float* gN1 = Ng + goff1;

    char* wb = smem + wave * 24576;          // wave-private staging

    const short8* wp = (const short8*)Wp + lane + (size_t)c0 * NT * 64;

    f32x4 aU[MT][NT], aV[MT][NT];
#pragma unroll
    for (int mt = 0; mt < MT; ++mt)
#pragma unroll
        for (int t = 0; t < NT; ++t) {
            aU[mt][t] = (f32x4){0.f, 0.f, 0.f, 0.f};
            aV[mt][t] = (f32x4){0.f, 0.f, 0.f, 0.f};
        }

    // buf layout (12KB): mt0 {A@0,A@1024,P@2048,P@3072,N@4096,N@5120},
    //                    mt1 same +6144.
#define STAGE(cc, bufoff)                                   \
    do {                                                    \
        const int _o = (cc) * 32;                           \
        char* _b = wb + (bufoff);                           \
        gll16(gA0 + _o,     _b);                            \
        gll16(gA0 + _o + 4, _b + 1024);                     \
        gll16(gP0 + _o,     _b + 2048);                     \
        gll16(gP0 + _o + 4, _b + 3072);                     \
        gll16(gN0 + _o,     _b + 4096);                     \
        gll16(gN0 + _o + 4, _b + 5120);                     \
        gll16(gA1 + _o,     _b + 6144);                     \
        gll16(gA1 + _o + 4, _b + 7168);                     \
        gll16(gP1 + _o,     _b + 8192);                     \
        gll16(gP1 + _o + 4, _b + 9216);                     \
        gll16(gN1 + _o,     _b + 10240);                    \
        gll16(gN1 + _o + 4, _b + 11264);                    \
    } while (0)

    // Load 8 W fragments for chunk cc into WF (names static; full unroll)
#define LOADW(WF, cc)                                       \
    do {                                                    \
        _Pragma("unroll")                                   \
        for (int t = 0; t < NT; ++t)                        \
            WF[t] = wp[(cc) * 512 + t * 64];                \
    } while (0)

    // pack u=a-p, v=a-n to bf16 and run 16 MFMAs for one m-tile
#define PACK_MFMA(mt, ya0, ya1, yp0, yp1, yn0, yn1, WF)                 \
    do {                                                                \
        f32x4 ul = (ya0) - (yp0), uh = (ya1) - (yp1);                   \
        f32x4 vl = (ya0) - (yn0), vh = (ya1) - (yn1);                   \
        u32x4 uw, vw;                                                   \
        uw[0] = cvtpk(ul[0], ul[1]); uw[1] = cvtpk(ul[2], ul[3]);       \
        uw[2] = cvtpk(uh[0], uh[1]); uw[3] = cvtpk(uh[2], uh[3]);       \
        vw[0] = cvtpk(vl[0], vl[1]); vw[1] = cvtpk(vl[2], vl[3]);       \
        vw[2] = cvtpk(vh[0], vh[1]); vw[3] = cvtpk(vh[2], vh[3]);       \
        short8 uf = __builtin_bit_cast(short8, uw);                     \
        short8 vf = __builtin_bit_cast(short8, vw);                     \
        _Pragma("unroll")                                               \
        for (int t = 0; t < NT; ++t) {                                  \
            aU[mt][t] = __builtin_amdgcn_mfma_f32_16x16x32_bf16(uf, WF[t], aU[mt][t], 0, 0, 0); \
            aV[mt][t] = __builtin_amdgcn_mfma_f32_16x16x32_bf16(vf, WF[t], aV[mt][t], 0, 0, 0); \
        }                                                               \
    } while (0)

    // 12 fragment reads (both m-tiles) in ONE asm block, one lgkmcnt(0).
    // Outputs valid at block end (MFMA consumes them -> no hoist hazard);
    // "memory" clobber pins ordering vs global_load_lds buffer reuse.
#define COMPUTE(bufoff, WF)                                             \
    do {                                                                \
        const AS3 char* lp = (const AS3 char*)(wb + (bufoff) + lane * 16); \
        f32x4 x0, x1, x2, x3, x4, x5, x6, x7, x8, x9, x10, x11;         \
        asm volatile(                                                   \
            "ds_read_b128 %0, %12 offset:0\n\t"                         \
            "ds_read_b128 %1, %12 offset:1024\n\t"                      \
            "ds_read_b128 %2, %12 offset:2048\n\t"                      \
            "ds_read_b128 %3, %12 offset:3072\n\t"                      \
            "ds_read_b128 %4, %12 offset:4096\n\t"                      \
            "ds_read_b128 %5, %12 offset:5120\n\t"                      \
            "ds_read_b128 %6, %12 offset:6144\n\t"                      \
            "ds_read_b128 %7, %12 offset:7168\n\t"                      \
            "ds_read_b128 %8, %12 offset:8192\n\t"                      \
            "ds_read_b128 %9, %12 offset:9216\n\t"                      \
            "ds_read_b128 %10, %12 offset:10240\n\t"                    \
            "ds_read_b128 %11, %12 offset:11264\n\t"                    \
            "s_waitcnt lgkmcnt(0)"                                      \
            : "=&v"(x0), "=&v"(x1), "=&v"(x2), "=&v"(x3), "=&v"(x4),    \
              "=&v"(x5), "=&v"(x6), "=&v"(x7), "=&v"(x8), "=&v"(x9),    \
              "=&v"(x10), "=&v"(x11)                                    \
            : "v"(lp)                                                   \
            : "memory");                                                \
        PACK_MFMA(0, x0, x1, x2, x3, x4, x5, WF);                       \
        PACK_MFMA(1, x6, x7, x8, x9, x10, x11, WF);                     \
    } while (0)

    short8 wf0[NT], wf1[NT];

    // prologue: chunk 0 -> buf0, wf0
    STAGE(0, 0);
    LOADW(wf0, 0);

    // 2-phase unrolled main loop (CPW=18 even). Per phase:
    //   issue stage(next)+W(next), vmcnt(28) [= 8 W(cur) + 12 stage(next)
    //   + 8 W(next) younger than stage(cur) -> retires stage(cur), never
    //   drains the prefetch], then 12 ds_reads + pack + 32 MFMA.
#pragma unroll
    for (int h = 0; h < CPW / 2; ++h) {
        const int ce = 2 * h;            // even chunk: buf0, wf0
        const int co = 2 * h + 1;        // odd  chunk: buf1, wf1

        STAGE(co, 12288);
        LOADW(wf1, co);
        asm volatile("s_waitcnt vmcnt(28)" ::: "memory");
        COMPUTE(0, wf0);

        if (co + 1 < CPW) {
            STAGE(co + 1, 0);
            LOADW(wf0, co + 1);
            asm volatile("s_waitcnt vmcnt(28)" ::: "memory");
        } else {
            asm volatile("s_waitcnt vmcnt(0)" ::: "memory");  // tail, once
        }
        COMPUTE(12288, wf1);
    }

    __syncthreads();

    // ---- cross-wave fragment reduce: 4 -> 2 -> 1 (wave 0 holds sum),
    //      aliased onto the staging LDS (2 regions x 32KB = 64KB) ----
    float (*lds)[MT][2][NT][64][4] = (float(*)[MT][2][NT][64][4])(void*)smem;

#define STORE_FRAGS(r)                                              \
    do {                                                            \
        _Pragma("unroll")                                           \
        for (int mt = 0; mt < MT; ++mt)                             \
        { _Pragma("unroll")                                         \
          for (int t = 0; t < NT; ++t) {                            \
            *(f32x4*)&lds[r][mt][0][t][lane][0] = aU[mt][t];        \
            *(f32x4*)&lds[r][mt][1][t][lane][0] = aV[mt][t];        \
          } }                                                       \
    } while (0)
#define ADD_FRAGS(r)                                                \
    do {                                                            \
        _Pragma("unroll")                                           \
        for (int mt = 0; mt < MT; ++mt)                             \
        { _Pragma("unroll")                                         \
          for (int t = 0; t < NT; ++t) {                            \
            aU[mt][t] += *(const f32x4*)&lds[r][mt][0][t][lane][0]; \
            aV[mt][t] += *(const f32x4*)&lds[r][mt][1][t][lane][0]; \
          } }                                                       \
    } while (0)

    if (wave >= 2) STORE_FRAGS(wave - 2);    // waves 2,3 -> regions 0,1
    __syncthreads();
    if (wave < 2) ADD_FRAGS(wave);
    __syncthreads();
    if (wave == 1) STORE_FRAGS(0);
    __syncthreads();

    if (wave == 0) {
        ADD_FRAGS(0);
        float du[MT][4], dv[MT][4];
#pragma unroll
        for (int mt = 0; mt < MT; ++mt)
#pragma unroll
            for (int r = 0; r < 4; ++r) { du[mt][r] = 0.f; dv[mt][r] = 0.f; }
#pragma unroll
        for (int mt = 0; mt < MT; ++mt)
#pragma unroll
            for (int t = 0; t < NT; ++t)
#pragma unroll
                for (int r = 0; r < 4; ++r) {
                    du[mt][r] += aU[mt][t][r] * aU[mt][t][r];
                    dv[mt][r] += aV[mt][t][r] * aV[mt][t][r];
                }
#pragma unroll
        for (int msk = 1; msk < 16; msk <<= 1)
#pragma unroll
            for (int mt = 0; mt < MT; ++mt)
#pragma unroll
                for (int r = 0; r < 4; ++r) {
                    du[mt][r] += __shfl_xor(du[mt][r], msk, 64);
                    dv[mt][r] += __shfl_xor(dv[mt][r], msk, 64);
                }
        float s = 0.f;
#pragma unroll
        for (int mt = 0; mt < MT; ++mt)
#pragma unroll
            for (int r = 0; r < 4; ++r) {
                float l = du[mt][r] - dv[mt][r] + ALPHA;
                s += l > 0.f ? l : 0.f;
            }
        s += __shfl_xor(s, 16, 64);
        s += __shfl_xor(s, 32, 64);
        if (lane == 0) atomicAdd(out, s * (1.0f / BATCH));
    }
}

extern "C" void kernel_launch(void* const* d_in, const int* in_sizes, int n_in,
                              void* d_out, int out_size, void* d_ws, size_t ws_size,
                              hipStream_t stream) {
    const float* A  = (const float*)d_in[0];
    const float* P  = (const float*)d_in[1];
    const float* Ng = (const float*)d_in[2];
    const float* W  = (const float*)d_in[3];
    unsigned short* Wp = (unsigned short*)d_ws;   // 72*8*64*8 bf16 = 589,824 B

    hipMemsetAsync(d_out, 0, sizeof(float), stream);

    pack_w_kernel<<<(KDIM * EMBD) / 256, 256, 0, stream>>>(W, Wp);
    triplet_kernel<<<BATCH / 32, 256, 0, stream>>>(A, P, Ng, Wp, (float*)d_out);
}